// Round 3
// baseline (78.591 us; speedup 1.0000x reference)
//
#include <hip/hip_runtime.h>
#include <hip/hip_bf16.h>
#include <math.h>

#define TB 4096   // batch
#define TN 39     // fields
#define TM 32     // embed dim
#define TD 32     // product layer dim
#define TH 400    // hidden width
#define BN_EPS 1e-3f

#define KT0 2     // layer-0 K=64  -> 2 chunks of K32
#define KTH 13    // layers 1/2 K=400 padded to 416 -> 13 chunks of K32

typedef __attribute__((ext_vector_type(8))) short bf16x8;
typedef __attribute__((ext_vector_type(4))) float f32x4;

// ---- fp32 -> bf16 hi/lo split ----
__device__ __forceinline__ ushort bf16_rn(float x) {
    __hip_bfloat16 h = __float2bfloat16(x);
    union { __hip_bfloat16 b; ushort u; } c; c.b = h; return c.u;
}
__device__ __forceinline__ void split2(float x, ushort& hi, ushort& lo) {
    unsigned xb = __float_as_uint(x);
    unsigned hb = xb & 0xFFFF0000u;
    hi = (ushort)(hb >> 16);
    lo = bf16_rn(x - __uint_as_float(hb));
}

// MFMA 16x16x32 bf16 fragment layout. Panels: [tile16][kt32][lane 64][j 8]
// ushorts; one (tile,kt) chunk = 512 ushorts = 1 KB.
__device__ __forceinline__ size_t panel_idx(int p, int k, int KT) {
    int lane_ = (p & 15) + 16 * ((k >> 2) & 3);
    int j_    = (k & 3) + 4 * ((k >> 4) & 1);
    return (((size_t)((p >> 4) * KT + (k >> 5)) * 64) + lane_) * 8 + j_;
}

// ---------------------------------------------------------------------------
// Front kernel:
//  blocks [0,1024): gather + l_z + l_p -> A0 panels (hi/lo)
//  blocks [1024,...): prepack W0/W1/W2 -> B panels; fold BN -> AC arrays
// ---------------------------------------------------------------------------
__global__ __launch_bounds__(256) void fused_front_kernel(
    const int*   __restrict__ fidx,
    const float* __restrict__ emb,
    const float* __restrict__ lin_w,
    const float* __restrict__ quad_w,
    const float* __restrict__ W0, const float* __restrict__ W1, const float* __restrict__ W2,
    const float* __restrict__ b0_, const float* __restrict__ g0_, const float* __restrict__ be0_,
    const float* __restrict__ rm0_, const float* __restrict__ rv0_,
    const float* __restrict__ b1_, const float* __restrict__ g1_, const float* __restrict__ be1_,
    const float* __restrict__ rm1_, const float* __restrict__ rv1_,
    const float* __restrict__ b2_, const float* __restrict__ g2_, const float* __restrict__ be2_,
    const float* __restrict__ rm2_, const float* __restrict__ rv2_,
    ushort* __restrict__ A0h, ushort* __restrict__ A0l,
    ushort* __restrict__ B0h, ushort* __restrict__ B0l,
    ushort* __restrict__ B1h, ushort* __restrict__ B1l,
    ushort* __restrict__ B2h, ushort* __restrict__ B2l,
    float* __restrict__ AC)
{
    if (blockIdx.x >= TB / 4) {
        int tid = (blockIdx.x - TB / 4) * 256 + threadIdx.x;
        const int NW0 = 64 * 112, NW = 416 * 112;
        if (tid < NW0 + 2 * NW) {
            const float* W; ushort *Ph, *Pl; int k, n4, K, KT;
            if (tid < NW0) {
                W = W0; Ph = B0h; Pl = B0l; k = tid / 112; n4 = tid % 112; K = 64; KT = KT0;
            } else if (tid < NW0 + NW) {
                int u = tid - NW0;
                W = W1; Ph = B1h; Pl = B1l; k = u / 112; n4 = u % 112; K = TH; KT = KTH;
            } else {
                int u = tid - NW0 - NW;
                W = W2; Ph = B2h; Pl = B2l; k = u / 112; n4 = u % 112; K = TH; KT = KTH;
            }
            int n0 = n4 * 4;
            float4 w = make_float4(0.f, 0.f, 0.f, 0.f);
            if (k < K && n0 < TH)
                w = *(const float4*)&W[(size_t)k * TH + n0];
            float vals[4] = {w.x, w.y, w.z, w.w};
            #pragma unroll
            for (int i = 0; i < 4; ++i) {
                ushort hi, lo; split2(vals[i], hi, lo);
                size_t idx = panel_idx(n0 + i, k, KT);
                Ph[idx] = hi; Pl[idx] = lo;
            }
        } else if (tid < NW0 + 2 * NW + 3 * 448) {
            int u = tid - NW0 - 2 * NW;
            int layer = u / 448, h = u % 448;
            const float *gp, *bep, *rmp, *rvp, *bp;
            if (layer == 0)      { gp = g0_; bep = be0_; rmp = rm0_; rvp = rv0_; bp = b0_; }
            else if (layer == 1) { gp = g1_; bep = be1_; rmp = rm1_; rvp = rv1_; bp = b1_; }
            else                 { gp = g2_; bep = be2_; rmp = rm2_; rvp = rv2_; bp = b2_; }
            float aj = 0.f, cj = 0.f;
            if (h < TH) {
                aj = gp[h] * rsqrtf(rvp[h] + BN_EPS);
                cj = (bp[h] - rmp[h]) * aj + bep[h];
            }
            AC[layer * 896 + h] = aj;
            AC[layer * 896 + 448 + h] = cj;
        }
        return;
    }

    // ---------------- gather + product path ----------------
    constexpr int R = 4;
    __shared__ float e_s[R][TN * TM];
    __shared__ int   idx_s[R][TN];
    __shared__ float s_s[R][TN];

    const int t  = threadIdx.x;
    const int b0 = blockIdx.x * R;

    if (t < R * TN) {
        int r = t / TN, n = t - r * TN;
        idx_s[r][n] = fidx[(b0 + r) * TN + n];
    }
    __syncthreads();

    for (int r = 0; r < R; ++r) {
        for (int k4 = t; k4 < TN * TM / 4; k4 += 256) {
            int n = k4 >> 3;
            long long base = (long long)idx_s[r][n] * TM + ((k4 & 7) << 2);
            *(float4*)&e_s[r][k4 * 4] = *(const float4*)&emb[base];
        }
    }
    __syncthreads();

    // l_z
    {
        const int d = t >> 3, j = t & 7;
        float acc[R] = {0.f, 0.f, 0.f, 0.f};
        const float* lw_base = lin_w + d * (TN * TM);
        #pragma unroll 4
        for (int i = 0; i < TN; ++i) {
            float4 lw = *(const float4*)&lw_base[i * 32 + j * 4];
            #pragma unroll
            for (int r = 0; r < R; ++r) {
                float4 e4 = *(const float4*)&e_s[r][i * 32 + j * 4];
                acc[r] = fmaf(lw.x, e4.x, acc[r]);
                acc[r] = fmaf(lw.y, e4.y, acc[r]);
                acc[r] = fmaf(lw.z, e4.z, acc[r]);
                acc[r] = fmaf(lw.w, e4.w, acc[r]);
            }
        }
        #pragma unroll
        for (int off = 1; off < 8; off <<= 1)
            #pragma unroll
            for (int r = 0; r < R; ++r)
                acc[r] += __shfl_xor(acc[r], off);
        if (j == 0) {
            #pragma unroll
            for (int r = 0; r < R; ++r) {
                ushort hi, lo; split2(acc[r], hi, lo);
                size_t idx = panel_idx(b0 + r, d, KT0);
                A0h[idx] = hi; A0l[idx] = lo;
            }
        }
    }

    // s[n] = sum_m e^2
    {
        int r = t >> 6, lane = t & 63;
        if (lane < TN) {
            float s = 0.f;
            #pragma unroll
            for (int mm = 0; mm < TM; ++mm) {
                float v = e_s[r][lane * TM + ((lane + mm) & 31)];
                s = fmaf(v, v, s);
            }
            s_s[r][lane] = s;
        }
    }
    __syncthreads();

    // l_p
    if (t < R * TD) {
        int r = t >> 5, d = t & 31;
        float accv = 0.f;
        for (int n = 0; n < TN; ++n) {
            float q = quad_w[d * TN + n];
            accv = fmaf(s_s[r][n], q * q, accv);
        }
        ushort hi, lo; split2(accv, hi, lo);
        size_t idx = panel_idx(b0 + r, TD + d, KT0);
        A0h[idx] = hi; A0l[idx] = lo;
    }
}

// ---------------------------------------------------------------------------
// One K=416 split-bf16 layer: acc[7] (wave's 16x112 slice), A from LDS,
// B double-buffered from global.
// ---------------------------------------------------------------------------
__device__ __forceinline__ void run_layer13(
    const ushort* __restrict__ Bh, const ushort* __restrict__ Bl,
    const ushort* Ah_s, const ushort* Al_s, int wave, int lane, f32x4 acc[7])
{
    #pragma unroll
    for (int nt = 0; nt < 7; ++nt)
        acc[nt] = (f32x4){0.f, 0.f, 0.f, 0.f};

    const ushort* base_h = Bh + (size_t)(wave * 7) * KTH * 512 + lane * 8;
    const ushort* base_l = Bl + (size_t)(wave * 7) * KTH * 512 + lane * 8;

    bf16x8 bh[2][7], bl[2][7];
    #pragma unroll
    for (int nt = 0; nt < 7; ++nt) {
        bh[0][nt] = *(const bf16x8*)(base_h + (size_t)(nt * KTH) * 512);
        bl[0][nt] = *(const bf16x8*)(base_l + (size_t)(nt * KTH) * 512);
    }
    #pragma unroll
    for (int kt = 0; kt < KTH; ++kt) {
        const int cur = kt & 1, nx = cur ^ 1;
        if (kt < KTH - 1) {
            #pragma unroll
            for (int nt = 0; nt < 7; ++nt) {
                bh[nx][nt] = *(const bf16x8*)(base_h + (size_t)(nt * KTH + kt + 1) * 512);
                bl[nx][nt] = *(const bf16x8*)(base_l + (size_t)(nt * KTH + kt + 1) * 512);
            }
        }
        bf16x8 ah = *(const bf16x8*)&Ah_s[kt * 512 + lane * 8];
        bf16x8 al = *(const bf16x8*)&Al_s[kt * 512 + lane * 8];
        #pragma unroll
        for (int nt = 0; nt < 7; ++nt) {
            acc[nt] = __builtin_amdgcn_mfma_f32_16x16x32_bf16(ah, bh[cur][nt], acc[nt], 0, 0, 0);
            acc[nt] = __builtin_amdgcn_mfma_f32_16x16x32_bf16(ah, bl[cur][nt], acc[nt], 0, 0, 0);
            acc[nt] = __builtin_amdgcn_mfma_f32_16x16x32_bf16(al, bh[cur][nt], acc[nt], 0, 0, 0);
        }
    }
}

// BN+ReLU epilogue, write activations into LDS in A-fragment layout.
__device__ __forceinline__ void epilogue_to_lds(
    const f32x4 acc[7], const float* __restrict__ ACl,
    int wave, int lane, ushort* Ah_s, ushort* Al_s)
{
    const int col = lane & 15, rq = (lane >> 4) << 2;
    #pragma unroll
    for (int nt = 0; nt < 7; ++nt) {
        int h = wave * 112 + nt * 16 + col;
        float aj = ACl[h], cj = ACl[448 + h];
        if (h < 416) {
            #pragma unroll
            for (int r = 0; r < 4; ++r) {
                float y = fmaxf(fmaf(acc[nt][r], aj, cj), 0.f);
                ushort hi, lo; split2(y, hi, lo);
                int row = rq + r;
                int addr = (h >> 5) * 512 + (row + 16 * ((h >> 2) & 3)) * 8
                         + (h & 3) + 4 * ((h >> 4) & 1);
                Ah_s[addr] = hi; Al_s[addr] = lo;
            }
        }
    }
}

// ---------------------------------------------------------------------------
// Fused MLP: layer0 + layer1 + layer2 + out-dot + sigmoid.
// 256 blocks x 256 threads; block = 16 batch rows; wave = 112-col slice.
// ---------------------------------------------------------------------------
__global__ __launch_bounds__(256, 1) void fused_mlp_kernel(
    const ushort* __restrict__ A0h, const ushort* __restrict__ A0l,
    const ushort* __restrict__ B0h, const ushort* __restrict__ B0l,
    const ushort* __restrict__ B1h, const ushort* __restrict__ B1l,
    const ushort* __restrict__ B2h, const ushort* __restrict__ B2l,
    const float* __restrict__ AC,
    const float* __restrict__ Wout, const float* __restrict__ bout,
    float* __restrict__ out)
{
    __shared__ ushort Ah_s[KTH * 512];
    __shared__ ushort Al_s[KTH * 512];
    __shared__ float  red[16][4];

    const int lane = threadIdx.x & 63;
    const int wave = threadIdx.x >> 6;
    const int mt   = blockIdx.x;

    f32x4 acc[7];

    // ---- layer 0 (K=64, A from global panels) ----
    bf16x8 a0h[2], a0l[2];
    #pragma unroll
    for (int kt = 0; kt < KT0; ++kt) {
        a0h[kt] = *(const bf16x8*)(A0h + (size_t)(mt * KT0 + kt) * 512 + lane * 8);
        a0l[kt] = *(const bf16x8*)(A0l + (size_t)(mt * KT0 + kt) * 512 + lane * 8);
    }
    #pragma unroll
    for (int nt = 0; nt < 7; ++nt) {
        acc[nt] = (f32x4){0.f, 0.f, 0.f, 0.f};
        int ntile = wave * 7 + nt;
        #pragma unroll
        for (int kt = 0; kt < KT0; ++kt) {
            bf16x8 bh = *(const bf16x8*)(B0h + (size_t)(ntile * KT0 + kt) * 512 + lane * 8);
            bf16x8 bl = *(const bf16x8*)(B0l + (size_t)(ntile * KT0 + kt) * 512 + lane * 8);
            acc[nt] = __builtin_amdgcn_mfma_f32_16x16x32_bf16(a0h[kt], bh, acc[nt], 0, 0, 0);
            acc[nt] = __builtin_amdgcn_mfma_f32_16x16x32_bf16(a0h[kt], bl, acc[nt], 0, 0, 0);
            acc[nt] = __builtin_amdgcn_mfma_f32_16x16x32_bf16(a0l[kt], bh, acc[nt], 0, 0, 0);
        }
    }
    epilogue_to_lds(acc, AC + 0, wave, lane, Ah_s, Al_s);
    __syncthreads();

    // ---- layer 1 ----
    run_layer13(B1h, B1l, Ah_s, Al_s, wave, lane, acc);
    __syncthreads();                       // all reads of Ah_s/Al_s done
    epilogue_to_lds(acc, AC + 896, wave, lane, Ah_s, Al_s);
    __syncthreads();

    // ---- layer 2 ----
    run_layer13(B2h, B2l, Ah_s, Al_s, wave, lane, acc);

    // ---- out: BN+ReLU fused into dot with Wout, then sigmoid ----
    {
        const float* AC2 = AC + 1792;
        const int col = lane & 15, rq = (lane >> 4) << 2;
        float partial[4] = {0.f, 0.f, 0.f, 0.f};
        #pragma unroll
        for (int nt = 0; nt < 7; ++nt) {
            int h = wave * 112 + nt * 16 + col;
            float aj = AC2[h], cj = AC2[448 + h];
            float wv = (h < TH) ? Wout[h] : 0.f;
            #pragma unroll
            for (int r = 0; r < 4; ++r) {
                float y = fmaxf(fmaf(acc[nt][r], aj, cj), 0.f);
                partial[r] = fmaf(y, wv, partial[r]);
            }
        }
        #pragma unroll
        for (int off = 1; off < 16; off <<= 1)
            #pragma unroll
            for (int r = 0; r < 4; ++r)
                partial[r] += __shfl_xor(partial[r], off);
        if (col == 0) {
            #pragma unroll
            for (int r = 0; r < 4; ++r)
                red[rq + r][wave] = partial[r];
        }
    }
    __syncthreads();
    if (threadIdx.x < 16) {
        float s = red[threadIdx.x][0] + red[threadIdx.x][1]
                + red[threadIdx.x][2] + red[threadIdx.x][3] + bout[0];
        out[mt * 16 + threadIdx.x] = 1.f / (1.f + expf(-s));
    }
}

// ---------------------------------------------------------------------------
extern "C" void kernel_launch(void* const* d_in, const int* in_sizes, int n_in,
                              void* d_out, int out_size, void* d_ws, size_t ws_size,
                              hipStream_t stream) {
    const int*   fidx   = (const int*)  d_in[0];
    const float* emb    = (const float*)d_in[2];
    const float* lin_w  = (const float*)d_in[3];
    const float* quad_w = (const float*)d_in[4];

    const float* W0  = (const float*)d_in[5];
    const float* b0  = (const float*)d_in[6];
    const float* g0  = (const float*)d_in[7];
    const float* be0 = (const float*)d_in[8];
    const float* rm0 = (const float*)d_in[9];
    const float* rv0 = (const float*)d_in[10];

    const float* W1  = (const float*)d_in[11];
    const float* b1  = (const float*)d_in[12];
    const float* g1  = (const float*)d_in[13];
    const float* be1 = (const float*)d_in[14];
    const float* rm1 = (const float*)d_in[15];
    const float* rv1 = (const float*)d_in[16];

    const float* W2  = (const float*)d_in[17];
    const float* b2  = (const float*)d_in[18];
    const float* g2  = (const float*)d_in[19];
    const float* be2 = (const float*)d_in[20];
    const float* rm2 = (const float*)d_in[21];
    const float* rv2 = (const float*)d_in[22];

    const float* Wout = (const float*)d_in[23];
    const float* bout = (const float*)d_in[24];

    const size_t SZ_A0 = (size_t)256 * KT0 * 512;
    const size_t SZ_B0 = (size_t)28  * KT0 * 512;
    const size_t SZ_B  = (size_t)28  * KTH * 512;

    ushort* p = (ushort*)d_ws;
    ushort *A0h = p; p += SZ_A0; ushort *A0l = p; p += SZ_A0;
    ushort *B0h = p; p += SZ_B0; ushort *B0l = p; p += SZ_B0;
    ushort *B1h = p; p += SZ_B;  ushort *B1l = p; p += SZ_B;
    ushort *B2h = p; p += SZ_B;  ushort *B2l = p; p += SZ_B;
    float*  AC  = (float*)p;     // 3 * 896 floats

    fused_front_kernel<<<TB / 4 + 398, 256, 0, stream>>>(
        fidx, emb, lin_w, quad_w, W0, W1, W2,
        b0, g0, be0, rm0, rv0,
        b1, g1, be1, rm1, rv1,
        b2, g2, be2, rm2, rv2,
        A0h, A0l, B0h, B0l, B1h, B1l, B2h, B2l, AC);

    fused_mlp_kernel<<<256, 256, 0, stream>>>(
        A0h, A0l, B0h, B0l, B1h, B1l, B2h, B2l, AC, Wout, bout, (float*)d_out);
}

// Round 4
// 65.377 us; speedup vs baseline: 1.2021x; 1.2021x over previous
//
#include <hip/hip_runtime.h>
#include <hip/hip_bf16.h>
#include <math.h>

#define TB 4096   // batch
#define TN 39     // fields
#define TM 32     // embed dim
#define TD 32     // product layer dim
#define TH 400    // hidden width
#define BN_EPS 1e-3f

#define KT0 2     // layer-0 K=64  -> 2 chunks of K32
#define KTH 13    // layers 1/2 K=400 padded to 416 -> 13 chunks of K32

typedef __attribute__((ext_vector_type(8))) short bf16x8;
typedef __attribute__((ext_vector_type(4))) float f32x4;

// ---- fp32 -> bf16 hi/lo split ----
__device__ __forceinline__ ushort bf16_rn(float x) {
    __hip_bfloat16 h = __float2bfloat16(x);
    union { __hip_bfloat16 b; ushort u; } c; c.b = h; return c.u;
}
__device__ __forceinline__ void split2(float x, ushort& hi, ushort& lo) {
    unsigned xb = __float_as_uint(x);
    unsigned hb = xb & 0xFFFF0000u;
    hi = (ushort)(hb >> 16);
    lo = bf16_rn(x - __uint_as_float(hb));
}

// MFMA 16x16x32 bf16 fragment layout. Panels: [tile16][kt32][lane 64][j 8]
// ushorts; one (tile,kt) chunk = 512 ushorts = 1 KB.
__device__ __forceinline__ size_t panel_idx(int p, int k, int KT) {
    int lane_ = (p & 15) + 16 * ((k >> 2) & 3);
    int j_    = (k & 3) + 4 * ((k >> 4) & 1);
    return (((size_t)((p >> 4) * KT + (k >> 5)) * 64) + lane_) * 8 + j_;
}

// ---------------------------------------------------------------------------
// Front kernel:
//  blocks [0,512): gather (8 rows/block) + l_z + l_p -> A0 panels (hi/lo)
//  blocks [512,910): prepack W0/W1/W2 -> B panels; fold BN -> AC arrays
// ---------------------------------------------------------------------------
#define RGB 8   // rows per gather block

__global__ __launch_bounds__(256) void fused_front_kernel(
    const int*   __restrict__ fidx,
    const float* __restrict__ emb,
    const float* __restrict__ lin_w,
    const float* __restrict__ quad_w,
    const float* __restrict__ W0, const float* __restrict__ W1, const float* __restrict__ W2,
    const float* __restrict__ b0_, const float* __restrict__ g0_, const float* __restrict__ be0_,
    const float* __restrict__ rm0_, const float* __restrict__ rv0_,
    const float* __restrict__ b1_, const float* __restrict__ g1_, const float* __restrict__ be1_,
    const float* __restrict__ rm1_, const float* __restrict__ rv1_,
    const float* __restrict__ b2_, const float* __restrict__ g2_, const float* __restrict__ be2_,
    const float* __restrict__ rm2_, const float* __restrict__ rv2_,
    ushort* __restrict__ A0h, ushort* __restrict__ A0l,
    ushort* __restrict__ B0h, ushort* __restrict__ B0l,
    ushort* __restrict__ B1h, ushort* __restrict__ B1l,
    ushort* __restrict__ B2h, ushort* __restrict__ B2l,
    float* __restrict__ AC)
{
    if (blockIdx.x >= TB / RGB) {
        int tid = (blockIdx.x - TB / RGB) * 256 + threadIdx.x;
        const int NW0 = 64 * 112, NW = 416 * 112;
        if (tid < NW0 + 2 * NW) {
            const float* W; ushort *Ph, *Pl; int k, n4, K, KT;
            if (tid < NW0) {
                W = W0; Ph = B0h; Pl = B0l; k = tid / 112; n4 = tid % 112; K = 64; KT = KT0;
            } else if (tid < NW0 + NW) {
                int u = tid - NW0;
                W = W1; Ph = B1h; Pl = B1l; k = u / 112; n4 = u % 112; K = TH; KT = KTH;
            } else {
                int u = tid - NW0 - NW;
                W = W2; Ph = B2h; Pl = B2l; k = u / 112; n4 = u % 112; K = TH; KT = KTH;
            }
            int n0 = n4 * 4;
            float4 w = make_float4(0.f, 0.f, 0.f, 0.f);
            if (k < K && n0 < TH)
                w = *(const float4*)&W[(size_t)k * TH + n0];
            float vals[4] = {w.x, w.y, w.z, w.w};
            #pragma unroll
            for (int i = 0; i < 4; ++i) {
                ushort hi, lo; split2(vals[i], hi, lo);
                size_t idx = panel_idx(n0 + i, k, KT);
                Ph[idx] = hi; Pl[idx] = lo;
            }
        } else if (tid < NW0 + 2 * NW + 3 * 448) {
            int u = tid - NW0 - 2 * NW;
            int layer = u / 448, h = u % 448;
            const float *gp, *bep, *rmp, *rvp, *bp;
            if (layer == 0)      { gp = g0_; bep = be0_; rmp = rm0_; rvp = rv0_; bp = b0_; }
            else if (layer == 1) { gp = g1_; bep = be1_; rmp = rm1_; rvp = rv1_; bp = b1_; }
            else                 { gp = g2_; bep = be2_; rmp = rm2_; rvp = rv2_; bp = b2_; }
            float aj = 0.f, cj = 0.f;
            if (h < TH) {
                aj = gp[h] * rsqrtf(rvp[h] + BN_EPS);
                cj = (bp[h] - rmp[h]) * aj + bep[h];
            }
            AC[layer * 896 + h] = aj;
            AC[layer * 896 + 448 + h] = cj;
        }
        return;
    }

    // ---------------- gather + product path ----------------
    __shared__ float e_s[RGB][TN * TM];     // 8 x 1248 floats = 39 KB
    __shared__ int   idx_s[RGB][TN];
    __shared__ float s_s[RGB][TN];

    const int t  = threadIdx.x;
    const int b0 = blockIdx.x * RGB;

    for (int u = t; u < RGB * TN; u += 256) {
        int r = u / TN, n = u - r * TN;
        idx_s[r][n] = fidx[(b0 + r) * TN + n];
    }
    __syncthreads();

    for (int r = 0; r < RGB; ++r) {
        for (int k4 = t; k4 < TN * TM / 4; k4 += 256) {
            int n = k4 >> 3;
            long long base = (long long)idx_s[r][n] * TM + ((k4 & 7) << 2);
            *(float4*)&e_s[r][k4 * 4] = *(const float4*)&emb[base];
        }
    }
    __syncthreads();

    // l_z: thread (d = t>>3, j = t&7), 8 rows per thread
    {
        const int d = t >> 3, j = t & 7;
        float acc[RGB];
        #pragma unroll
        for (int r = 0; r < RGB; ++r) acc[r] = 0.f;
        const float* lw_base = lin_w + d * (TN * TM);
        #pragma unroll 2
        for (int i = 0; i < TN; ++i) {
            float4 lw = *(const float4*)&lw_base[i * 32 + j * 4];
            #pragma unroll
            for (int r = 0; r < RGB; ++r) {
                float4 e4 = *(const float4*)&e_s[r][i * 32 + j * 4];
                acc[r] = fmaf(lw.x, e4.x, acc[r]);
                acc[r] = fmaf(lw.y, e4.y, acc[r]);
                acc[r] = fmaf(lw.z, e4.z, acc[r]);
                acc[r] = fmaf(lw.w, e4.w, acc[r]);
            }
        }
        #pragma unroll
        for (int off = 1; off < 8; off <<= 1)
            #pragma unroll
            for (int r = 0; r < RGB; ++r)
                acc[r] += __shfl_xor(acc[r], off);
        if (j == 0) {
            #pragma unroll
            for (int r = 0; r < RGB; ++r) {
                ushort hi, lo; split2(acc[r], hi, lo);
                size_t idx = panel_idx(b0 + r, d, KT0);
                A0h[idx] = hi; A0l[idx] = lo;
            }
        }
    }

    // s[n] = sum_m e^2 (diagonal to dodge bank conflicts)
    {
        int r = t >> 5, sub = t & 31;
        for (int n = sub; n < TN; n += 32) {
            float s = 0.f;
            #pragma unroll
            for (int mm = 0; mm < TM; ++mm) {
                float v = e_s[r][n * TM + ((n + mm) & 31)];
                s = fmaf(v, v, s);
            }
            s_s[r][n] = s;
        }
    }
    __syncthreads();

    // l_p: r = t>>5 (0..7), d = t&31
    {
        int r = t >> 5, d = t & 31;
        float accv = 0.f;
        for (int n = 0; n < TN; ++n) {
            float q = quad_w[d * TN + n];
            accv = fmaf(s_s[r][n], q * q, accv);
        }
        ushort hi, lo; split2(accv, hi, lo);
        size_t idx = panel_idx(b0 + r, TD + d, KT0);
        A0h[idx] = hi; A0l[idx] = lo;
    }
}

// ---------------------------------------------------------------------------
// GEMM v3: 256-thread blocks, 4 waves = 2 N-halves x 2 K-halves of a 64x64
// output tile. K-halves reduced via LDS. BN+ReLU fused; PANEL_OUT repacks
// into next layer's A-fragment panels via LDS transpose.
// ---------------------------------------------------------------------------
template <int KT, bool PANEL_OUT>
__global__ __launch_bounds__(256) void gemm_layer_v3(
    const ushort* __restrict__ Ah, const ushort* __restrict__ Al,
    const ushort* __restrict__ Bh, const ushort* __restrict__ Bl,
    const float* __restrict__ ACl,        // a[448], c[448] for this layer
    ushort* __restrict__ Nh, ushort* __restrict__ Nl,
    float* __restrict__ Yout)
{
    constexpr int KH = (KT + 1) / 2;
    __shared__ f32x4 red[2 * 512];        // 2 n-halves x 8 frags x 64 lanes
    __shared__ float ysm[64][68];         // used only when PANEL_OUT

    const int lane = threadIdx.x & 63;
    const int wave = threadIdx.x >> 6;
    const int ksel = wave & 1;
    const int nsel = wave >> 1;
    const int bm = blockIdx.x & 63;
    const int bn = blockIdx.x >> 6;

    const int kt0 = ksel ? KH : 0;
    const int kt1 = ksel ? KT : KH;

    f32x4 acc[4][2];
    #pragma unroll
    for (int m = 0; m < 4; ++m)
        #pragma unroll
        for (int n = 0; n < 2; ++n)
            acc[m][n] = (f32x4){0.f, 0.f, 0.f, 0.f};

    const size_t lo8 = (size_t)lane * 8;
    const ushort* pAh = Ah + (size_t)(bm * 4) * KT * 512 + lo8;
    const ushort* pAl = Al + (size_t)(bm * 4) * KT * 512 + lo8;
    const ushort* pBh = Bh + (size_t)(bn * 4 + nsel * 2) * KT * 512 + lo8;
    const ushort* pBl = Bl + (size_t)(bn * 4 + nsel * 2) * KT * 512 + lo8;

    #pragma unroll 2
    for (int kt = kt0; kt < kt1; ++kt) {
        bf16x8 ah[4], al[4], bh2[2], bl2[2];
        #pragma unroll
        for (int m = 0; m < 4; ++m) {
            ah[m] = *(const bf16x8*)(pAh + (size_t)(m * KT + kt) * 512);
            al[m] = *(const bf16x8*)(pAl + (size_t)(m * KT + kt) * 512);
        }
        #pragma unroll
        for (int n = 0; n < 2; ++n) {
            bh2[n] = *(const bf16x8*)(pBh + (size_t)(n * KT + kt) * 512);
            bl2[n] = *(const bf16x8*)(pBl + (size_t)(n * KT + kt) * 512);
        }
        #pragma unroll
        for (int m = 0; m < 4; ++m)
            #pragma unroll
            for (int n = 0; n < 2; ++n) {
                acc[m][n] = __builtin_amdgcn_mfma_f32_16x16x32_bf16(ah[m], bh2[n], acc[m][n], 0, 0, 0);
                acc[m][n] = __builtin_amdgcn_mfma_f32_16x16x32_bf16(ah[m], bl2[n], acc[m][n], 0, 0, 0);
                acc[m][n] = __builtin_amdgcn_mfma_f32_16x16x32_bf16(al[m], bh2[n], acc[m][n], 0, 0, 0);
            }
    }

    // K-half reduction through LDS
    if (ksel == 1) {
        #pragma unroll
        for (int m = 0; m < 4; ++m)
            #pragma unroll
            for (int n = 0; n < 2; ++n)
                red[nsel * 512 + (m * 2 + n) * 64 + lane] = acc[m][n];
    }
    __syncthreads();

    if (ksel == 0) {
        const int col = lane & 15, rq = (lane >> 4) << 2;
        #pragma unroll
        for (int m = 0; m < 4; ++m)
            #pragma unroll
            for (int n = 0; n < 2; ++n) {
                f32x4 p = red[nsel * 512 + (m * 2 + n) * 64 + lane];
                f32x4 o = acc[m][n];
                int h = bn * 64 + (nsel * 2 + n) * 16 + col;
                float aj = ACl[h], cj = ACl[448 + h];
                #pragma unroll
                for (int r = 0; r < 4; ++r) {
                    float y = fmaxf(fmaf(o[r] + p[r], aj, cj), 0.f);
                    if constexpr (PANEL_OUT) {
                        ysm[m * 16 + rq + r][(nsel * 2 + n) * 16 + col] = y;
                    } else {
                        if (h < TH)
                            Yout[(size_t)(bm * 64 + m * 16 + rq + r) * TH + h] = y;
                    }
                }
            }
    }

    if constexpr (PANEL_OUT) {
        __syncthreads();
        if (wave < 2) {
            const int ck = wave;
            const int kt32 = bn * 2 + ck;
            if (kt32 < KTH) {
                const int kq = (lane >> 4) << 2;
                #pragma unroll
                for (int mtl = 0; mtl < 4; ++mtl) {
                    int row_l = mtl * 16 + (lane & 15);
                    int kb = ck * 32 + kq;
                    float4 v0 = *(const float4*)&ysm[row_l][kb];
                    float4 v1 = *(const float4*)&ysm[row_l][kb + 16];
                    ushort h_[8], l_[8];
                    split2(v0.x, h_[0], l_[0]); split2(v0.y, h_[1], l_[1]);
                    split2(v0.z, h_[2], l_[2]); split2(v0.w, h_[3], l_[3]);
                    split2(v1.x, h_[4], l_[4]); split2(v1.y, h_[5], l_[5]);
                    split2(v1.z, h_[6], l_[6]); split2(v1.w, h_[7], l_[7]);
                    uint4 H, L;
                    H.x = (uint)h_[0] | ((uint)h_[1] << 16);
                    H.y = (uint)h_[2] | ((uint)h_[3] << 16);
                    H.z = (uint)h_[4] | ((uint)h_[5] << 16);
                    H.w = (uint)h_[6] | ((uint)h_[7] << 16);
                    L.x = (uint)l_[0] | ((uint)l_[1] << 16);
                    L.y = (uint)l_[2] | ((uint)l_[3] << 16);
                    L.z = (uint)l_[4] | ((uint)l_[5] << 16);
                    L.w = (uint)l_[6] | ((uint)l_[7] << 16);
                    size_t base = (((size_t)(bm * 4 + mtl) * KTH + kt32) * 64 + lane) * 8;
                    *(uint4*)(Nh + base) = H;
                    *(uint4*)(Nl + base) = L;
                }
            }
        }
    }
}

// ---------------------------------------------------------------------------
// out = sigmoid(X @ Wout + bout). One wave per batch row.
// ---------------------------------------------------------------------------
__global__ __launch_bounds__(256) void out_kernel(
    const float* __restrict__ X,      // B x TH
    const float* __restrict__ Wout,   // TH
    const float* __restrict__ bout,   // 1
    float* __restrict__ out)          // B
{
    const int wave = threadIdx.x >> 6;
    const int lane = threadIdx.x & 63;
    const int row  = blockIdx.x * 4 + wave;

    float s = 0.f;
    for (int k = lane; k < TH; k += 64)
        s = fmaf(X[row * TH + k], Wout[k], s);
    #pragma unroll
    for (int off = 32; off; off >>= 1)
        s += __shfl_xor(s, off);
    if (lane == 0)
        out[row] = 1.f / (1.f + expf(-(s + bout[0])));
}

// ---------------------------------------------------------------------------
extern "C" void kernel_launch(void* const* d_in, const int* in_sizes, int n_in,
                              void* d_out, int out_size, void* d_ws, size_t ws_size,
                              hipStream_t stream) {
    const int*   fidx   = (const int*)  d_in[0];
    const float* emb    = (const float*)d_in[2];
    const float* lin_w  = (const float*)d_in[3];
    const float* quad_w = (const float*)d_in[4];

    const float* W0  = (const float*)d_in[5];
    const float* b0  = (const float*)d_in[6];
    const float* g0  = (const float*)d_in[7];
    const float* be0 = (const float*)d_in[8];
    const float* rm0 = (const float*)d_in[9];
    const float* rv0 = (const float*)d_in[10];

    const float* W1  = (const float*)d_in[11];
    const float* b1  = (const float*)d_in[12];
    const float* g1  = (const float*)d_in[13];
    const float* be1 = (const float*)d_in[14];
    const float* rm1 = (const float*)d_in[15];
    const float* rv1 = (const float*)d_in[16];

    const float* W2  = (const float*)d_in[17];
    const float* b2  = (const float*)d_in[18];
    const float* g2  = (const float*)d_in[19];
    const float* be2 = (const float*)d_in[20];
    const float* rm2 = (const float*)d_in[21];
    const float* rv2 = (const float*)d_in[22];

    const float* Wout = (const float*)d_in[23];
    const float* bout = (const float*)d_in[24];

    const size_t SZ_A0 = (size_t)256 * KT0 * 512;
    const size_t SZ_A  = (size_t)256 * KTH * 512;
    const size_t SZ_B0 = (size_t)28  * KT0 * 512;
    const size_t SZ_B  = (size_t)28  * KTH * 512;

    ushort* p = (ushort*)d_ws;
    ushort *A0h = p; p += SZ_A0; ushort *A0l = p; p += SZ_A0;
    ushort *A1h = p; p += SZ_A;  ushort *A1l = p; p += SZ_A;
    ushort *A2h = p; p += SZ_A;  ushort *A2l = p; p += SZ_A;
    ushort *B0h = p; p += SZ_B0; ushort *B0l = p; p += SZ_B0;
    ushort *B1h = p; p += SZ_B;  ushort *B1l = p; p += SZ_B;
    ushort *B2h = p; p += SZ_B;  ushort *B2l = p; p += SZ_B;
    float*  AC  = (float*)p;                 // 3 * 896 floats
    float*  Y3  = AC + 3 * 896;              // 4096 x 400 fp32

    fused_front_kernel<<<TB / RGB + 398, 256, 0, stream>>>(
        fidx, emb, lin_w, quad_w, W0, W1, W2,
        b0, g0, be0, rm0, rv0,
        b1, g1, be1, rm1, rv1,
        b2, g2, be2, rm2, rv2,
        A0h, A0l, B0h, B0l, B1h, B1l, B2h, B2l, AC);

    gemm_layer_v3<KT0, true><<<448, 256, 0, stream>>>(
        A0h, A0l, B0h, B0l, AC + 0, A1h, A1l, nullptr);
    gemm_layer_v3<KTH, true><<<448, 256, 0, stream>>>(
        A1h, A1l, B1h, B1l, AC + 896, A2h, A2l, nullptr);
    gemm_layer_v3<KTH, false><<<448, 256, 0, stream>>>(
        A2h, A2l, B2h, B2l, AC + 1792, nullptr, nullptr, Y3);

    out_kernel<<<TB / 4, 256, 0, stream>>>(Y3, Wout, bout, (float*)d_out);
}

// Round 5
// 53.979 us; speedup vs baseline: 1.4560x; 1.2112x over previous
//
#include <hip/hip_runtime.h>
#include <hip/hip_bf16.h>
#include <math.h>

#define TB 4096   // batch
#define TN 39     // fields
#define TM 32     // embed dim
#define TD 32     // product layer dim
#define TH 400    // hidden width
#define BN_EPS 1e-3f

#define KT0 2     // layer-0 K=64  -> 2 chunks of K32
#define KTH 13    // layers 1/2 K=400 padded to 416 -> 13 chunks of K32

typedef __attribute__((ext_vector_type(8))) short bf16x8;
typedef __attribute__((ext_vector_type(4))) float f32x4;

// ---- fp32 -> bf16 hi/lo split ----
__device__ __forceinline__ ushort bf16_rn(float x) {
    __hip_bfloat16 h = __float2bfloat16(x);
    union { __hip_bfloat16 b; ushort u; } c; c.b = h; return c.u;
}
__device__ __forceinline__ void split2(float x, ushort& hi, ushort& lo) {
    unsigned xb = __float_as_uint(x);
    unsigned hb = xb & 0xFFFF0000u;
    hi = (ushort)(hb >> 16);
    lo = bf16_rn(x - __uint_as_float(hb));
}

// MFMA 16x16x32 bf16 fragment layout. Panels: [tile16][kt32][lane 64][j 8]
// ushorts; one (tile,kt) chunk = 512 ushorts = 1 KB.
__device__ __forceinline__ size_t panel_idx(int p, int k, int KT) {
    int lane_ = (p & 15) + 16 * ((k >> 2) & 3);
    int j_    = (k & 3) + 4 * ((k >> 4) & 1);
    return (((size_t)((p >> 4) * KT + (k >> 5)) * 64) + lane_) * 8 + j_;
}

// ---------------------------------------------------------------------------
// Front kernel (verified round-2 body, R=4):
//  blocks [0,1024): gather + l_z + l_p -> A0 panels (hi/lo)
//  blocks [1024,1422): prepack W0/W1/W2 -> B panels; fold BN -> AC arrays
// ---------------------------------------------------------------------------
__global__ __launch_bounds__(256) void fused_front_kernel(
    const int*   __restrict__ fidx,
    const float* __restrict__ emb,
    const float* __restrict__ lin_w,
    const float* __restrict__ quad_w,
    const float* __restrict__ W0, const float* __restrict__ W1, const float* __restrict__ W2,
    const float* __restrict__ b0_, const float* __restrict__ g0_, const float* __restrict__ be0_,
    const float* __restrict__ rm0_, const float* __restrict__ rv0_,
    const float* __restrict__ b1_, const float* __restrict__ g1_, const float* __restrict__ be1_,
    const float* __restrict__ rm1_, const float* __restrict__ rv1_,
    const float* __restrict__ b2_, const float* __restrict__ g2_, const float* __restrict__ be2_,
    const float* __restrict__ rm2_, const float* __restrict__ rv2_,
    ushort* __restrict__ A0h, ushort* __restrict__ A0l,
    ushort* __restrict__ B0h, ushort* __restrict__ B0l,
    ushort* __restrict__ B1h, ushort* __restrict__ B1l,
    ushort* __restrict__ B2h, ushort* __restrict__ B2l,
    float* __restrict__ AC)
{
    if (blockIdx.x >= TB / 4) {
        int tid = (blockIdx.x - TB / 4) * 256 + threadIdx.x;
        const int NW0 = 64 * 112, NW = 416 * 112;
        if (tid < NW0 + 2 * NW) {
            const float* W; ushort *Ph, *Pl; int k, n4, K, KT;
            if (tid < NW0) {
                W = W0; Ph = B0h; Pl = B0l; k = tid / 112; n4 = tid % 112; K = 64; KT = KT0;
            } else if (tid < NW0 + NW) {
                int u = tid - NW0;
                W = W1; Ph = B1h; Pl = B1l; k = u / 112; n4 = u % 112; K = TH; KT = KTH;
            } else {
                int u = tid - NW0 - NW;
                W = W2; Ph = B2h; Pl = B2l; k = u / 112; n4 = u % 112; K = TH; KT = KTH;
            }
            int n0 = n4 * 4;
            float4 w = make_float4(0.f, 0.f, 0.f, 0.f);
            if (k < K && n0 < TH)
                w = *(const float4*)&W[(size_t)k * TH + n0];
            float vals[4] = {w.x, w.y, w.z, w.w};
            #pragma unroll
            for (int i = 0; i < 4; ++i) {
                ushort hi, lo; split2(vals[i], hi, lo);
                size_t idx = panel_idx(n0 + i, k, KT);
                Ph[idx] = hi; Pl[idx] = lo;
            }
        } else if (tid < NW0 + 2 * NW + 3 * 448) {
            int u = tid - NW0 - 2 * NW;
            int layer = u / 448, h = u % 448;
            const float *gp, *bep, *rmp, *rvp, *bp;
            if (layer == 0)      { gp = g0_; bep = be0_; rmp = rm0_; rvp = rv0_; bp = b0_; }
            else if (layer == 1) { gp = g1_; bep = be1_; rmp = rm1_; rvp = rv1_; bp = b1_; }
            else                 { gp = g2_; bep = be2_; rmp = rm2_; rvp = rv2_; bp = b2_; }
            float aj = 0.f, cj = 0.f;
            if (h < TH) {
                aj = gp[h] * rsqrtf(rvp[h] + BN_EPS);
                cj = (bp[h] - rmp[h]) * aj + bep[h];
            }
            AC[layer * 896 + h] = aj;
            AC[layer * 896 + 448 + h] = cj;
        }
        return;
    }

    // ---------------- gather + product path ----------------
    constexpr int R = 4;
    __shared__ float e_s[R][TN * TM];
    __shared__ int   idx_s[R][TN];
    __shared__ float s_s[R][TN];

    const int t  = threadIdx.x;
    const int b0 = blockIdx.x * R;

    if (t < R * TN) {
        int r = t / TN, n = t - r * TN;
        idx_s[r][n] = fidx[(b0 + r) * TN + n];
    }
    __syncthreads();

    for (int r = 0; r < R; ++r) {
        for (int k4 = t; k4 < TN * TM / 4; k4 += 256) {
            int n = k4 >> 3;
            long long base = (long long)idx_s[r][n] * TM + ((k4 & 7) << 2);
            *(float4*)&e_s[r][k4 * 4] = *(const float4*)&emb[base];
        }
    }
    __syncthreads();

    // l_z
    {
        const int d = t >> 3, j = t & 7;
        float acc[R] = {0.f, 0.f, 0.f, 0.f};
        const float* lw_base = lin_w + d * (TN * TM);
        #pragma unroll 4
        for (int i = 0; i < TN; ++i) {
            float4 lw = *(const float4*)&lw_base[i * 32 + j * 4];
            #pragma unroll
            for (int r = 0; r < R; ++r) {
                float4 e4 = *(const float4*)&e_s[r][i * 32 + j * 4];
                acc[r] = fmaf(lw.x, e4.x, acc[r]);
                acc[r] = fmaf(lw.y, e4.y, acc[r]);
                acc[r] = fmaf(lw.z, e4.z, acc[r]);
                acc[r] = fmaf(lw.w, e4.w, acc[r]);
            }
        }
        #pragma unroll
        for (int off = 1; off < 8; off <<= 1)
            #pragma unroll
            for (int r = 0; r < R; ++r)
                acc[r] += __shfl_xor(acc[r], off);
        if (j == 0) {
            #pragma unroll
            for (int r = 0; r < R; ++r) {
                ushort hi, lo; split2(acc[r], hi, lo);
                size_t idx = panel_idx(b0 + r, d, KT0);
                A0h[idx] = hi; A0l[idx] = lo;
            }
        }
    }

    // s[n] = sum_m e^2
    {
        int r = t >> 6, lane = t & 63;
        if (lane < TN) {
            float s = 0.f;
            #pragma unroll
            for (int mm = 0; mm < TM; ++mm) {
                float v = e_s[r][lane * TM + ((lane + mm) & 31)];
                s = fmaf(v, v, s);
            }
            s_s[r][lane] = s;
        }
    }
    __syncthreads();

    // l_p
    if (t < R * TD) {
        int r = t >> 5, d = t & 31;
        float accv = 0.f;
        for (int n = 0; n < TN; ++n) {
            float q = quad_w[d * TN + n];
            accv = fmaf(s_s[r][n], q * q, accv);
        }
        ushort hi, lo; split2(accv, hi, lo);
        size_t idx = panel_idx(b0 + r, TD + d, KT0);
        A0h[idx] = hi; A0l[idx] = lo;
    }
}

// ---------------------------------------------------------------------------
// GEMM v5: 128-thread blocks (2 waves), each wave owns a 32x32 output slice
// of the block's 32x64 tile (2 mt x 2 nt fragments). 896 blocks/layer =
// 1792 waves. No K-split, no cross-wave reduction.
// OUTMODE 0: BN+ReLU -> repack into next layer's A panels (via ysm transpose).
// OUTMODE 1: BN+ReLU -> dot with Wout -> per-(row, bn, wave) partials to P.
// ---------------------------------------------------------------------------
template <int KT, int OUTMODE>
__global__ __launch_bounds__(128) void gemm_layer_v5(
    const ushort* __restrict__ Ah, const ushort* __restrict__ Al,
    const ushort* __restrict__ Bh, const ushort* __restrict__ Bl,
    const float* __restrict__ ACl,
    ushort* __restrict__ Nh, ushort* __restrict__ Nl,
    const float* __restrict__ Wout,
    float* __restrict__ P)
{
    const int lane = threadIdx.x & 63;
    const int nsel = threadIdx.x >> 6;     // wave id: which 32-col half
    const int bm = blockIdx.x;             // 0..127 (32-row tiles)
    const int bn = blockIdx.y;             // 0..6   (64-col tiles)

    f32x4 acc[2][2];
    #pragma unroll
    for (int m = 0; m < 2; ++m)
        #pragma unroll
        for (int n = 0; n < 2; ++n)
            acc[m][n] = (f32x4){0.f, 0.f, 0.f, 0.f};

    const size_t lo8 = (size_t)lane * 8;
    const ushort* pAh = Ah + (size_t)(bm * 2) * KT * 512 + lo8;
    const ushort* pAl = Al + (size_t)(bm * 2) * KT * 512 + lo8;
    const ushort* pBh = Bh + (size_t)(bn * 4 + nsel * 2) * KT * 512 + lo8;
    const ushort* pBl = Bl + (size_t)(bn * 4 + nsel * 2) * KT * 512 + lo8;

    #pragma unroll 2
    for (int kt = 0; kt < KT; ++kt) {
        bf16x8 ah[2], al[2], bh[2], bl[2];
        #pragma unroll
        for (int m = 0; m < 2; ++m) {
            ah[m] = *(const bf16x8*)(pAh + (size_t)(m * KT + kt) * 512);
            al[m] = *(const bf16x8*)(pAl + (size_t)(m * KT + kt) * 512);
        }
        #pragma unroll
        for (int n = 0; n < 2; ++n) {
            bh[n] = *(const bf16x8*)(pBh + (size_t)(n * KT + kt) * 512);
            bl[n] = *(const bf16x8*)(pBl + (size_t)(n * KT + kt) * 512);
        }
        #pragma unroll
        for (int m = 0; m < 2; ++m)
            #pragma unroll
            for (int n = 0; n < 2; ++n) {
                acc[m][n] = __builtin_amdgcn_mfma_f32_16x16x32_bf16(ah[m], bh[n], acc[m][n], 0, 0, 0);
                acc[m][n] = __builtin_amdgcn_mfma_f32_16x16x32_bf16(ah[m], bl[n], acc[m][n], 0, 0, 0);
                acc[m][n] = __builtin_amdgcn_mfma_f32_16x16x32_bf16(al[m], bh[n], acc[m][n], 0, 0, 0);
            }
    }

    const int col = lane & 15, rq = (lane >> 4) << 2;

    if constexpr (OUTMODE == 0) {
        __shared__ float ysm[32][68];
        #pragma unroll
        for (int m = 0; m < 2; ++m)
            #pragma unroll
            for (int n = 0; n < 2; ++n) {
                int h = bn * 64 + (nsel * 2 + n) * 16 + col;
                float aj = ACl[h], cj = ACl[448 + h];
                #pragma unroll
                for (int r = 0; r < 4; ++r)
                    ysm[m * 16 + rq + r][(nsel * 2 + n) * 16 + col] =
                        fmaxf(fmaf(acc[m][n][r], aj, cj), 0.f);
            }
        __syncthreads();

        const int ck = nsel;
        const int kt32 = bn * 2 + ck;
        if (kt32 < KTH) {
            #pragma unroll
            for (int mtl = 0; mtl < 2; ++mtl) {
                int row_l = mtl * 16 + (lane & 15);
                int kb = ck * 32 + rq;
                float4 v0 = *(const float4*)&ysm[row_l][kb];
                float4 v1 = *(const float4*)&ysm[row_l][kb + 16];
                ushort h_[8], l_[8];
                split2(v0.x, h_[0], l_[0]); split2(v0.y, h_[1], l_[1]);
                split2(v0.z, h_[2], l_[2]); split2(v0.w, h_[3], l_[3]);
                split2(v1.x, h_[4], l_[4]); split2(v1.y, h_[5], l_[5]);
                split2(v1.z, h_[6], l_[6]); split2(v1.w, h_[7], l_[7]);
                uint4 H, L;
                H.x = (uint)h_[0] | ((uint)h_[1] << 16);
                H.y = (uint)h_[2] | ((uint)h_[3] << 16);
                H.z = (uint)h_[4] | ((uint)h_[5] << 16);
                H.w = (uint)h_[6] | ((uint)h_[7] << 16);
                L.x = (uint)l_[0] | ((uint)l_[1] << 16);
                L.y = (uint)l_[2] | ((uint)l_[3] << 16);
                L.z = (uint)l_[4] | ((uint)l_[5] << 16);
                L.w = (uint)l_[6] | ((uint)l_[7] << 16);
                size_t base = (((size_t)(bm * 2 + mtl) * KTH + kt32) * 64 + lane) * 8;
                *(uint4*)(Nh + base) = H;
                *(uint4*)(Nl + base) = L;
            }
        }
    } else {
        // Fused final-layer epilogue: y = relu(bn(acc)); partial = sum_h y*Wout[h]
        float partial[2][4] = {{0.f,0.f,0.f,0.f},{0.f,0.f,0.f,0.f}};
        #pragma unroll
        for (int m = 0; m < 2; ++m)
            #pragma unroll
            for (int n = 0; n < 2; ++n) {
                int h = bn * 64 + (nsel * 2 + n) * 16 + col;
                float aj = ACl[h], cj = ACl[448 + h];
                float wv = (h < TH) ? Wout[h] : 0.f;
                #pragma unroll
                for (int r = 0; r < 4; ++r) {
                    float y = fmaxf(fmaf(acc[m][n][r], aj, cj), 0.f);
                    partial[m][r] = fmaf(y, wv, partial[m][r]);
                }
            }
        #pragma unroll
        for (int off = 1; off < 16; off <<= 1)
            #pragma unroll
            for (int m = 0; m < 2; ++m)
                #pragma unroll
                for (int r = 0; r < 4; ++r)
                    partial[m][r] += __shfl_xor(partial[m][r], off);
        if (col == 0) {
            #pragma unroll
            for (int m = 0; m < 2; ++m)
                #pragma unroll
                for (int r = 0; r < 4; ++r)
                    P[(size_t)(bm * 32 + m * 16 + rq + r) * 16 + bn * 2 + nsel] =
                        partial[m][r];
        }
    }
}

// ---------------------------------------------------------------------------
// fin: out[row] = sigmoid(sum_{i<14} P[row][i] + bout)
// ---------------------------------------------------------------------------
__global__ __launch_bounds__(256) void fin_kernel(
    const float* __restrict__ P, const float* __restrict__ bout,
    float* __restrict__ out)
{
    int row = blockIdx.x * 256 + threadIdx.x;
    const float* p = P + (size_t)row * 16;
    float s = bout[0];
    #pragma unroll
    for (int i = 0; i < 14; ++i) s += p[i];
    out[row] = 1.f / (1.f + expf(-s));
}

// ---------------------------------------------------------------------------
extern "C" void kernel_launch(void* const* d_in, const int* in_sizes, int n_in,
                              void* d_out, int out_size, void* d_ws, size_t ws_size,
                              hipStream_t stream) {
    const int*   fidx   = (const int*)  d_in[0];
    const float* emb    = (const float*)d_in[2];
    const float* lin_w  = (const float*)d_in[3];
    const float* quad_w = (const float*)d_in[4];

    const float* W0  = (const float*)d_in[5];
    const float* b0  = (const float*)d_in[6];
    const float* g0  = (const float*)d_in[7];
    const float* be0 = (const float*)d_in[8];
    const float* rm0 = (const float*)d_in[9];
    const float* rv0 = (const float*)d_in[10];

    const float* W1  = (const float*)d_in[11];
    const float* b1  = (const float*)d_in[12];
    const float* g1  = (const float*)d_in[13];
    const float* be1 = (const float*)d_in[14];
    const float* rm1 = (const float*)d_in[15];
    const float* rv1 = (const float*)d_in[16];

    const float* W2  = (const float*)d_in[17];
    const float* b2  = (const float*)d_in[18];
    const float* g2  = (const float*)d_in[19];
    const float* be2 = (const float*)d_in[20];
    const float* rm2 = (const float*)d_in[21];
    const float* rv2 = (const float*)d_in[22];

    const float* Wout = (const float*)d_in[23];
    const float* bout = (const float*)d_in[24];

    const size_t SZ_A0 = (size_t)256 * KT0 * 512;
    const size_t SZ_A  = (size_t)256 * KTH * 512;
    const size_t SZ_B0 = (size_t)28  * KT0 * 512;
    const size_t SZ_B  = (size_t)28  * KTH * 512;

    ushort* p = (ushort*)d_ws;
    ushort *A0h = p; p += SZ_A0; ushort *A0l = p; p += SZ_A0;
    ushort *A1h = p; p += SZ_A;  ushort *A1l = p; p += SZ_A;
    ushort *A2h = p; p += SZ_A;  ushort *A2l = p; p += SZ_A;
    ushort *B0h = p; p += SZ_B0; ushort *B0l = p; p += SZ_B0;
    ushort *B1h = p; p += SZ_B;  ushort *B1l = p; p += SZ_B;
    ushort *B2h = p; p += SZ_B;  ushort *B2l = p; p += SZ_B;
    float*  AC  = (float*)p;                 // 3 * 896 floats
    float*  Pst = AC + 3 * 896;              // 4096 x 16 partials

    fused_front_kernel<<<TB / 4 + 398, 256, 0, stream>>>(
        fidx, emb, lin_w, quad_w, W0, W1, W2,
        b0, g0, be0, rm0, rv0,
        b1, g1, be1, rm1, rv1,
        b2, g2, be2, rm2, rv2,
        A0h, A0l, B0h, B0l, B1h, B1l, B2h, B2l, AC);

    dim3 ggrid(128, 7);
    gemm_layer_v5<KT0, 0><<<ggrid, 128, 0, stream>>>(
        A0h, A0l, B0h, B0l, AC + 0, A1h, A1l, nullptr, nullptr);
    gemm_layer_v5<KTH, 0><<<ggrid, 128, 0, stream>>>(
        A1h, A1l, B1h, B1l, AC + 896, A2h, A2l, nullptr, nullptr);
    gemm_layer_v5<KTH, 1><<<ggrid, 128, 0, stream>>>(
        A2h, A2l, B2h, B2l, AC + 1792, nullptr, nullptr, Wout, Pst);

    fin_kernel<<<TB / 256, 256, 0, stream>>>(Pst, bout, (float*)d_out);
}

// Round 8
// 51.424 us; speedup vs baseline: 1.5283x; 1.0497x over previous
//
#include <hip/hip_runtime.h>
#include <hip/hip_bf16.h>
#include <math.h>

#define TB 4096   // batch
#define TN 39     // fields
#define TM 32     // embed dim
#define TD 32     // product layer dim
#define TH 400    // hidden width
#define BN_EPS 1e-3f

#define KT0 2     // layer-0 K=64  -> 2 chunks of K32
#define KTH 13    // layers 1/2 K=400 padded to 416 -> 13 chunks of K32

typedef __attribute__((ext_vector_type(8))) short bf16x8;
typedef __attribute__((ext_vector_type(4))) float f32x4;

// ---- fp32 -> bf16 hi/lo split ----
__device__ __forceinline__ ushort bf16_rn(float x) {
    __hip_bfloat16 h = __float2bfloat16(x);
    union { __hip_bfloat16 b; ushort u; } c; c.b = h; return c.u;
}
__device__ __forceinline__ void split2(float x, ushort& hi, ushort& lo) {
    unsigned xb = __float_as_uint(x);
    unsigned hb = xb & 0xFFFF0000u;
    hi = (ushort)(hb >> 16);
    lo = bf16_rn(x - __uint_as_float(hb));
}

// MFMA 16x16x32 bf16 fragment layout. Panels: [tile16][kt32][lane 64][j 8]
// ushorts; one (tile,kt) chunk = 512 ushorts = 1 KB.
__device__ __forceinline__ size_t panel_idx(int p, int k, int KT) {
    int lane_ = (p & 15) + 16 * ((k >> 2) & 3);
    int j_    = (k & 3) + 4 * ((k >> 4) & 1);
    return (((size_t)((p >> 4) * KT + (k >> 5)) * 64) + lane_) * 8 + j_;
}

// ---------------------------------------------------------------------------
// Front kernel (verified round-2 body, R=4):
//  blocks [0,1024): gather + l_z + l_p -> A0 panels (hi/lo)
//  blocks [1024,1422): prepack W0/W1/W2 -> B panels; fold BN -> AC arrays
// ---------------------------------------------------------------------------
__global__ __launch_bounds__(256) void fused_front_kernel(
    const int*   __restrict__ fidx,
    const float* __restrict__ emb,
    const float* __restrict__ lin_w,
    const float* __restrict__ quad_w,
    const float* __restrict__ W0, const float* __restrict__ W1, const float* __restrict__ W2,
    const float* __restrict__ b0_, const float* __restrict__ g0_, const float* __restrict__ be0_,
    const float* __restrict__ rm0_, const float* __restrict__ rv0_,
    const float* __restrict__ b1_, const float* __restrict__ g1_, const float* __restrict__ be1_,
    const float* __restrict__ rm1_, const float* __restrict__ rv1_,
    const float* __restrict__ b2_, const float* __restrict__ g2_, const float* __restrict__ be2_,
    const float* __restrict__ rm2_, const float* __restrict__ rv2_,
    ushort* __restrict__ A0h, ushort* __restrict__ A0l,
    ushort* __restrict__ B0h, ushort* __restrict__ B0l,
    ushort* __restrict__ B1h, ushort* __restrict__ B1l,
    ushort* __restrict__ B2h, ushort* __restrict__ B2l,
    float* __restrict__ AC)
{
    if (blockIdx.x >= TB / 4) {
        int tid = (blockIdx.x - TB / 4) * 256 + threadIdx.x;
        const int NW0 = 64 * 112, NW = 416 * 112;
        if (tid < NW0 + 2 * NW) {
            const float* W; ushort *Ph, *Pl; int k, n4, K, KT;
            if (tid < NW0) {
                W = W0; Ph = B0h; Pl = B0l; k = tid / 112; n4 = tid % 112; K = 64; KT = KT0;
            } else if (tid < NW0 + NW) {
                int u = tid - NW0;
                W = W1; Ph = B1h; Pl = B1l; k = u / 112; n4 = u % 112; K = TH; KT = KTH;
            } else {
                int u = tid - NW0 - NW;
                W = W2; Ph = B2h; Pl = B2l; k = u / 112; n4 = u % 112; K = TH; KT = KTH;
            }
            int n0 = n4 * 4;
            float4 w = make_float4(0.f, 0.f, 0.f, 0.f);
            if (k < K && n0 < TH)
                w = *(const float4*)&W[(size_t)k * TH + n0];
            float vals[4] = {w.x, w.y, w.z, w.w};
            #pragma unroll
            for (int i = 0; i < 4; ++i) {
                ushort hi, lo; split2(vals[i], hi, lo);
                size_t idx = panel_idx(n0 + i, k, KT);
                Ph[idx] = hi; Pl[idx] = lo;
            }
        } else if (tid < NW0 + 2 * NW + 3 * 448) {
            int u = tid - NW0 - 2 * NW;
            int layer = u / 448, h = u % 448;
            const float *gp, *bep, *rmp, *rvp, *bp;
            if (layer == 0)      { gp = g0_; bep = be0_; rmp = rm0_; rvp = rv0_; bp = b0_; }
            else if (layer == 1) { gp = g1_; bep = be1_; rmp = rm1_; rvp = rv1_; bp = b1_; }
            else                 { gp = g2_; bep = be2_; rmp = rm2_; rvp = rv2_; bp = b2_; }
            float aj = 0.f, cj = 0.f;
            if (h < TH) {
                aj = gp[h] * rsqrtf(rvp[h] + BN_EPS);
                cj = (bp[h] - rmp[h]) * aj + bep[h];
            }
            AC[layer * 896 + h] = aj;
            AC[layer * 896 + 448 + h] = cj;
        }
        return;
    }

    // ---------------- gather + product path ----------------
    constexpr int R = 4;
    __shared__ float e_s[R][TN * TM];
    __shared__ int   idx_s[R][TN];
    __shared__ float s_s[R][TN];

    const int t  = threadIdx.x;
    const int b0 = blockIdx.x * R;

    if (t < R * TN) {
        int r = t / TN, n = t - r * TN;
        idx_s[r][n] = fidx[(b0 + r) * TN + n];
    }
    __syncthreads();

    for (int r = 0; r < R; ++r) {
        for (int k4 = t; k4 < TN * TM / 4; k4 += 256) {
            int n = k4 >> 3;
            long long base = (long long)idx_s[r][n] * TM + ((k4 & 7) << 2);
            *(float4*)&e_s[r][k4 * 4] = *(const float4*)&emb[base];
        }
    }
    __syncthreads();

    // l_z
    {
        const int d = t >> 3, j = t & 7;
        float acc[R] = {0.f, 0.f, 0.f, 0.f};
        const float* lw_base = lin_w + d * (TN * TM);
        #pragma unroll 4
        for (int i = 0; i < TN; ++i) {
            float4 lw = *(const float4*)&lw_base[i * 32 + j * 4];
            #pragma unroll
            for (int r = 0; r < R; ++r) {
                float4 e4 = *(const float4*)&e_s[r][i * 32 + j * 4];
                acc[r] = fmaf(lw.x, e4.x, acc[r]);
                acc[r] = fmaf(lw.y, e4.y, acc[r]);
                acc[r] = fmaf(lw.z, e4.z, acc[r]);
                acc[r] = fmaf(lw.w, e4.w, acc[r]);
            }
        }
        #pragma unroll
        for (int off = 1; off < 8; off <<= 1)
            #pragma unroll
            for (int r = 0; r < R; ++r)
                acc[r] += __shfl_xor(acc[r], off);
        if (j == 0) {
            #pragma unroll
            for (int r = 0; r < R; ++r) {
                ushort hi, lo; split2(acc[r], hi, lo);
                size_t idx = panel_idx(b0 + r, d, KT0);
                A0h[idx] = hi; A0l[idx] = lo;
            }
        }
    }

    // s[n] = sum_m e^2
    {
        int r = t >> 6, lane = t & 63;
        if (lane < TN) {
            float s = 0.f;
            #pragma unroll
            for (int mm = 0; mm < TM; ++mm) {
                float v = e_s[r][lane * TM + ((lane + mm) & 31)];
                s = fmaf(v, v, s);
            }
            s_s[r][lane] = s;
        }
    }
    __syncthreads();

    // l_p
    if (t < R * TD) {
        int r = t >> 5, d = t & 31;
        float accv = 0.f;
        for (int n = 0; n < TN; ++n) {
            float q = quad_w[d * TN + n];
            accv = fmaf(s_s[r][n], q * q, accv);
        }
        ushort hi, lo; split2(accv, hi, lo);
        size_t idx = panel_idx(b0 + r, TD + d, KT0);
        A0h[idx] = hi; A0l[idx] = lo;
    }
}

// ---------------------------------------------------------------------------
// GEMM v6: 64x64 tile, 256 threads (4 waves, 2M x 2N quadrants of 32x32).
// 448 blocks/layer = 1792 waves. XCD-aware bijective swizzle: each XCD owns
// 8 bm-groups x all 7 bn, so A panels (832 KB/XCD) stay L2-resident across
// the bn sweep and B (728 KB) is replicated per XCD.
// OUTMODE 0: BN+ReLU -> repack into next layer's A panels (via ysm transpose).
// OUTMODE 1: BN+ReLU -> dot with Wout -> per-(row, bn, nsel) partials to P.
// ---------------------------------------------------------------------------
template <int KT, int OUTMODE>
__global__ __launch_bounds__(256) void gemm_layer_v6(
    const ushort* __restrict__ Ah, const ushort* __restrict__ Al,
    const ushort* __restrict__ Bh, const ushort* __restrict__ Bl,
    const float* __restrict__ ACl,
    ushort* __restrict__ Nh, ushort* __restrict__ Nl,
    const float* __restrict__ Wout,
    float* __restrict__ P)
{
    const int lane = threadIdx.x & 63;
    const int wv   = threadIdx.x >> 6;      // 0..3
    const int msel = wv >> 1;               // M half
    const int nsel = wv & 1;                // N half

    // XCD-aware bijective swizzle over 448 blocks (bm 0..63, bn 0..6)
    const int orig = blockIdx.x;
    const int xcd  = orig & 7;
    const int slot = orig >> 3;             // 0..55
    const int bm   = (slot & 7) * 8 + xcd;  // 0..63
    const int bn   = slot >> 3;             // 0..6

    f32x4 acc[2][2];
    #pragma unroll
    for (int m = 0; m < 2; ++m)
        #pragma unroll
        for (int n = 0; n < 2; ++n)
            acc[m][n] = (f32x4){0.f, 0.f, 0.f, 0.f};

    const size_t lo8 = (size_t)lane * 8;
    const ushort* pAh = Ah + (size_t)(bm * 4 + msel * 2) * KT * 512 + lo8;
    const ushort* pAl = Al + (size_t)(bm * 4 + msel * 2) * KT * 512 + lo8;
    const ushort* pBh = Bh + (size_t)(bn * 4 + nsel * 2) * KT * 512 + lo8;
    const ushort* pBl = Bl + (size_t)(bn * 4 + nsel * 2) * KT * 512 + lo8;

    #pragma unroll 2
    for (int kt = 0; kt < KT; ++kt) {
        bf16x8 ah[2], al[2], bh[2], bl[2];
        #pragma unroll
        for (int m = 0; m < 2; ++m) {
            ah[m] = *(const bf16x8*)(pAh + (size_t)(m * KT + kt) * 512);
            al[m] = *(const bf16x8*)(pAl + (size_t)(m * KT + kt) * 512);
        }
        #pragma unroll
        for (int n = 0; n < 2; ++n) {
            bh[n] = *(const bf16x8*)(pBh + (size_t)(n * KT + kt) * 512);
            bl[n] = *(const bf16x8*)(pBl + (size_t)(n * KT + kt) * 512);
        }
        #pragma unroll
        for (int m = 0; m < 2; ++m)
            #pragma unroll
            for (int n = 0; n < 2; ++n) {
                acc[m][n] = __builtin_amdgcn_mfma_f32_16x16x32_bf16(ah[m], bh[n], acc[m][n], 0, 0, 0);
                acc[m][n] = __builtin_amdgcn_mfma_f32_16x16x32_bf16(ah[m], bl[n], acc[m][n], 0, 0, 0);
                acc[m][n] = __builtin_amdgcn_mfma_f32_16x16x32_bf16(al[m], bh[n], acc[m][n], 0, 0, 0);
            }
    }

    const int col = lane & 15, rq = (lane >> 4) << 2;

    if constexpr (OUTMODE == 0) {
        __shared__ float ysm[64][68];
        #pragma unroll
        for (int m = 0; m < 2; ++m)
            #pragma unroll
            for (int n = 0; n < 2; ++n) {
                int h = bn * 64 + (nsel * 2 + n) * 16 + col;
                float aj = ACl[h], cj = ACl[448 + h];
                #pragma unroll
                for (int r = 0; r < 4; ++r)
                    ysm[msel * 32 + m * 16 + rq + r][(nsel * 2 + n) * 16 + col] =
                        fmaxf(fmaf(acc[m][n][r], aj, cj), 0.f);
            }
        __syncthreads();

        const int ck = wv & 1;
        const int kt32 = bn * 2 + ck;
        if (kt32 < KTH) {
            #pragma unroll
            for (int mi = 0; mi < 2; ++mi) {
                int mtl = (wv >> 1) * 2 + mi;    // 0..3
                int row_l = mtl * 16 + (lane & 15);
                int kb = ck * 32 + rq;
                float4 v0 = *(const float4*)&ysm[row_l][kb];
                float4 v1 = *(const float4*)&ysm[row_l][kb + 16];
                ushort h_[8], l_[8];
                split2(v0.x, h_[0], l_[0]); split2(v0.y, h_[1], l_[1]);
                split2(v0.z, h_[2], l_[2]); split2(v0.w, h_[3], l_[3]);
                split2(v1.x, h_[4], l_[4]); split2(v1.y, h_[5], l_[5]);
                split2(v1.z, h_[6], l_[6]); split2(v1.w, h_[7], l_[7]);
                uint4 H, L;
                H.x = (uint)h_[0] | ((uint)h_[1] << 16);
                H.y = (uint)h_[2] | ((uint)h_[3] << 16);
                H.z = (uint)h_[4] | ((uint)h_[5] << 16);
                H.w = (uint)h_[6] | ((uint)h_[7] << 16);
                L.x = (uint)l_[0] | ((uint)l_[1] << 16);
                L.y = (uint)l_[2] | ((uint)l_[3] << 16);
                L.z = (uint)l_[4] | ((uint)l_[5] << 16);
                L.w = (uint)l_[6] | ((uint)l_[7] << 16);
                size_t base = (((size_t)(bm * 4 + mtl) * KTH + kt32) * 64 + lane) * 8;
                *(uint4*)(Nh + base) = H;
                *(uint4*)(Nl + base) = L;
            }
        }
    } else {
        // Fused final-layer epilogue: y = relu(bn(acc)); partial = sum_h y*Wout[h]
        float partial[2][4] = {{0.f,0.f,0.f,0.f},{0.f,0.f,0.f,0.f}};
        #pragma unroll
        for (int m = 0; m < 2; ++m)
            #pragma unroll
            for (int n = 0; n < 2; ++n) {
                int h = bn * 64 + (nsel * 2 + n) * 16 + col;
                float aj = ACl[h], cj = ACl[448 + h];
                float wv_ = (h < TH) ? Wout[h] : 0.f;
                #pragma unroll
                for (int r = 0; r < 4; ++r) {
                    float y = fmaxf(fmaf(acc[m][n][r], aj, cj), 0.f);
                    partial[m][r] = fmaf(y, wv_, partial[m][r]);
                }
            }
        #pragma unroll
        for (int off = 1; off < 16; off <<= 1)
            #pragma unroll
            for (int m = 0; m < 2; ++m)
                #pragma unroll
                for (int r = 0; r < 4; ++r)
                    partial[m][r] += __shfl_xor(partial[m][r], off);
        if (col == 0) {
            #pragma unroll
            for (int m = 0; m < 2; ++m)
                #pragma unroll
                for (int r = 0; r < 4; ++r)
                    P[(size_t)(bm * 64 + msel * 32 + m * 16 + rq + r) * 16
                      + bn * 2 + nsel] = partial[m][r];
        }
    }
}

// ---------------------------------------------------------------------------
// fin: out[row] = sigmoid(sum_{i<14} P[row][i] + bout), float4 loads
// ---------------------------------------------------------------------------
__global__ __launch_bounds__(256) void fin_kernel(
    const float* __restrict__ P, const float* __restrict__ bout,
    float* __restrict__ out)
{
    int row = blockIdx.x * 256 + threadIdx.x;
    const float4* p = (const float4*)(P + (size_t)row * 16);
    float4 p0 = p[0], p1 = p[1], p2 = p[2], p3 = p[3];
    float s = bout[0]
            + p0.x + p0.y + p0.z + p0.w
            + p1.x + p1.y + p1.z + p1.w
            + p2.x + p2.y + p2.z + p2.w
            + p3.x + p3.y;
    out[row] = 1.f / (1.f + expf(-s));
}

// ---------------------------------------------------------------------------
extern "C" void kernel_launch(void* const* d_in, const int* in_sizes, int n_in,
                              void* d_out, int out_size, void* d_ws, size_t ws_size,
                              hipStream_t stream) {
    const int*   fidx   = (const int*)  d_in[0];
    const float* emb    = (const float*)d_in[2];
    const float* lin_w  = (const float*)d_in[3];
    const float* quad_w = (const float*)d_in[4];

    const float* W0  = (const float*)d_in[5];
    const float* b0  = (const float*)d_in[6];
    const float* g0  = (const float*)d_in[7];
    const float* be0 = (const float*)d_in[8];
    const float* rm0 = (const float*)d_in[9];
    const float* rv0 = (const float*)d_in[10];

    const float* W1  = (const float*)d_in[11];
    const float* b1  = (const float*)d_in[12];
    const float* g1  = (const float*)d_in[13];
    const float* be1 = (const float*)d_in[14];
    const float* rm1 = (const float*)d_in[15];
    const float* rv1 = (const float*)d_in[16];

    const float* W2  = (const float*)d_in[17];
    const float* b2  = (const float*)d_in[18];
    const float* g2  = (const float*)d_in[19];
    const float* be2 = (const float*)d_in[20];
    const float* rm2 = (const float*)d_in[21];
    const float* rv2 = (const float*)d_in[22];

    const float* Wout = (const float*)d_in[23];
    const float* bout = (const float*)d_in[24];

    const size_t SZ_A0 = (size_t)256 * KT0 * 512;
    const size_t SZ_A  = (size_t)256 * KTH * 512;
    const size_t SZ_B0 = (size_t)28  * KT0 * 512;
    const size_t SZ_B  = (size_t)28  * KTH * 512;

    ushort* p = (ushort*)d_ws;
    ushort *A0h = p; p += SZ_A0; ushort *A0l = p; p += SZ_A0;
    ushort *A1h = p; p += SZ_A;  ushort *A1l = p; p += SZ_A;
    ushort *A2h = p; p += SZ_A;  ushort *A2l = p; p += SZ_A;
    ushort *B0h = p; p += SZ_B0; ushort *B0l = p; p += SZ_B0;
    ushort *B1h = p; p += SZ_B;  ushort *B1l = p; p += SZ_B;
    ushort *B2h = p; p += SZ_B;  ushort *B2l = p; p += SZ_B;
    float*  AC  = (float*)p;                 // 3 * 896 floats
    float*  Pst = AC + 3 * 896;              // 4096 x 16 partials

    fused_front_kernel<<<TB / 4 + 398, 256, 0, stream>>>(
        fidx, emb, lin_w, quad_w, W0, W1, W2,
        b0, g0, be0, rm0, rv0,
        b1, g1, be1, rm1, rv1,
        b2, g2, be2, rm2, rv2,
        A0h, A0l, B0h, B0l, B1h, B1l, B2h, B2l, AC);

    gemm_layer_v6<KT0, 0><<<448, 256, 0, stream>>>(
        A0h, A0l, B0h, B0l, AC + 0, A1h, A1l, nullptr, nullptr);
    gemm_layer_v6<KTH, 0><<<448, 256, 0, stream>>>(
        A1h, A1l, B1h, B1l, AC + 896, A2h, A2l, nullptr, nullptr);
    gemm_layer_v6<KTH, 1><<<448, 256, 0, stream>>>(
        A2h, A2l, B2h, B2l, AC + 1792, nullptr, nullptr, Wout, Pst);

    fin_kernel<<<TB / 256, 256, 0, stream>>>(Pst, bout, (float*)d_out);
}